// Round 1
// baseline (93.380 us; speedup 1.0000x reference)
//
#include <hip/hip_runtime.h>
#include <math.h>

#define NC 5
#define EPS_F 0.1f

// One thread per row. q = x·Wᵀ + b (all > 0). Solve
//   min KL(p||q) s.t. KL(p||u) <= eps  on the simplex
// closed-form path p(t) = softmax(t · log q), t = 1/(1+lam).
//   f(t)   = t·E_p[u] - log Z + log n - eps      (u = log q - max log q)
//   f'(t)  = t·Var_p(u)
//   f''(t) = Var_p(u) + t·mu3_p(u)
// Bracketed HALLEY on t in [0,1] (cubic): 1 feasibility eval + 4 evals,
// output reuses the last eval's exps (no separate final-softmax pass).
// vs previous version: 10 softmax passes -> 5.
__global__ __launch_bounds__(256) void klproj_kernel(
    const float* __restrict__ x,
    const float* __restrict__ W,
    const float* __restrict__ b,
    float* __restrict__ out,
    int batch)
{
    int row = blockIdx.x * blockDim.x + threadIdx.x;
    if (row >= batch) return;

    // --- load x row (20 B/thread, contiguous across the wave) ---
    float xv[NC];
#pragma unroll
    for (int k = 0; k < NC; ++k) xv[k] = x[row * NC + k];

    // --- q_j = sum_k x_k W[j][k] + b_j ; u_j = log q_j - max (W,b uniform -> s_loads)
    float u[NC];
    float m = -1e30f;
#pragma unroll
    for (int j = 0; j < NC; ++j) {
        float q = b[j];
#pragma unroll
        for (int k = 0; k < NC; ++k) q = fmaf(xv[k], W[j * NC + k], q);
        float sj = __logf(q);
        u[j] = sj;
        m = fmaxf(m, sj);
    }
    // precompute u, u^2, u^3 once — reused by every eval
    float u2[NC], u3[NC];
#pragma unroll
    for (int j = 0; j < NC; ++j) {
        u[j] -= m;
        u2[j] = u[j] * u[j];
        u3[j] = u2[j] * u[j];
    }

    const float logn_eps = 1.6094379124341003f - EPS_F; // log(5) - eps

    // one softmax pass: e[], Z kept for the output; f, f', f'' for Halley
    float e[NC];
    float Z, f, fp, fpp;
    auto eval = [&](float t) {
        float T1 = 0.f, T2 = 0.f, T3 = 0.f;
        Z = 0.f;
#pragma unroll
        for (int j = 0; j < NC; ++j) {
            float ej = __expf(t * u[j]);
            e[j] = ej;
            Z += ej;
            T1 = fmaf(ej, u[j],  T1);
            T2 = fmaf(ej, u2[j], T2);
            T3 = fmaf(ej, u3[j], T3);
        }
        float rZ  = 1.0f / Z;
        float Eu  = T1 * rZ;
        float Eu2 = T2 * rZ;
        float Eu3 = T3 * rZ;
        float var = fmaf(-Eu, Eu, Eu2);                 // E[u^2] - E[u]^2
        float c   = fmaf(-2.0f * Eu, Eu, 3.0f * Eu2);   // 3E[u^2] - 2E[u]^2
        float mu3 = fmaf(-Eu, c, Eu3);                  // third central moment
        f   = fmaf(t, Eu, -__logf(Z)) + logn_eps;
        fp  = t * var;
        fpp = fmaf(t, mu3, var);
    };

    // feasibility at t=1 (lam=0); e[],Z stay valid for feasible lanes
    eval(1.0f);
    if (f > 0.f) {
        float lo = 0.f, hi = 1.0f;
        // Halley step from the t=1 evaluation (f>0, fp>0 => step left)
        float den  = fmaf(fp, fp, -0.5f * f * fpp);
        float cand = 1.0f - f * fp / den;
        // NaN-safe bracket guard (inverted-compare form)
        float t = (cand > lo && cand < hi) ? cand : 0.5f;
#pragma unroll
        for (int it = 0; it < 4; ++it) {
            eval(t);                      // last iteration's e[],Z are the output
            if (f > 0.f) hi = t; else lo = t;
            if (it < 3) {
                den  = fmaf(fp, fp, -0.5f * f * fpp);
                cand = t - f * fp / den;
                t = (cand > lo && cand < hi) ? cand : 0.5f * (lo + hi);
            }
        }
    }

    // output from the last eval's exps
    float rZ = 1.0f / Z;
#pragma unroll
    for (int j = 0; j < NC; ++j) out[row * NC + j] = e[j] * rZ;
}

extern "C" void kernel_launch(void* const* d_in, const int* in_sizes, int n_in,
                              void* d_out, int out_size, void* d_ws, size_t ws_size,
                              hipStream_t stream) {
    const float* x = (const float*)d_in[0];
    const float* W = (const float*)d_in[1];
    const float* b = (const float*)d_in[2];
    float* out = (float*)d_out;
    int batch = in_sizes[0] / NC;

    int block = 256;
    int grid = (batch + block - 1) / block;
    klproj_kernel<<<grid, block, 0, stream>>>(x, W, b, out, batch);
}